// Round 1
// baseline (281.953 us; speedup 1.0000x reference)
//
#include <hip/hip_runtime.h>
#include <math.h>

#define L_SEQ 192
#define H_DIM 768
#define B_SZ  8
#define NPAIR (L_SEQ * (L_SEQ + 1) / 2)   // 18528
#define MROWS (B_SZ * L_SEQ)              // 1536
#define NCOLS (2 * H_DIM)                 // 1536

// p -> (i, j) for triu_indices(L) in row-major order.
// off(i) = number of pairs before row i = i*(2L - i + 1)/2
__device__ __forceinline__ void pair_from_p(int p, int& io, int& jo) {
    float tl = 2.0f * L_SEQ + 1.0f;
    int i = (int)((tl - sqrtf(tl * tl - 8.0f * (float)p)) * 0.5f);
    if (i < 0) i = 0;
    if (i > L_SEQ - 1) i = L_SEQ - 1;
    while (i > 0 && i * (2 * L_SEQ - i + 1) / 2 > p) --i;
    while (i < L_SEQ - 1 && (i + 1) * (2 * L_SEQ - i) / 2 <= p) ++i;
    io = i;
    jo = i + (p - i * (2 * L_SEQ - i + 1) / 2);
}

// ---------------------------------------------------------------------------
// GEMM: D[m][n] = sum_k seq[m][k] * W[n mod 768][ (n>=768 ? 768 : 0) + k ]
//   seq viewed as [1536][768] (B*L rows), W is [768][1536], D is [1536][1536].
//   Columns n < 768  -> A = seq @ W[:, :768]^T   (the "repeat"/i side)
//   Columns n >= 768 -> C = seq @ W[:, 768:]^T   (the "visible"/j side)
// BM=BN=128, BK=16, 256 threads, 8x8 micro-tile per thread.
// ---------------------------------------------------------------------------
#define BM 128
#define BN 128
#define BK 16

__global__ __launch_bounds__(256) void gemm_f32_kernel(
    const float* __restrict__ Mmat,   // [1536][768]
    const float* __restrict__ W,      // [768][1536]
    float* __restrict__ D)            // [1536][1536]
{
    const int K = H_DIM, LDM = H_DIM, LDW = NCOLS, LDD = NCOLS;
    const int bn0 = blockIdx.x * BN;
    const int bm0 = blockIdx.y * BM;
    const int side = (bn0 >= H_DIM) ? 1 : 0;               // uniform: 768 % 128 == 0
    const float* Wbase = W + (size_t)(bn0 - side * H_DIM) * LDW + side * H_DIM;

    __shared__ float Ms[BK][BM + 4];   // transposed: Ms[k][row], stride 132
    __shared__ float Ns[BK][BN + 4];

    const int t  = threadIdx.x;
    const int tx = t & 15;
    const int ty = t >> 4;

    float acc[8][8] = {};

    for (int k0 = 0; k0 < K; k0 += BK) {
        // stage M tile (128 rows x 16 k) -> transposed LDS
        #pragma unroll
        for (int q = t; q < BM * BK / 4; q += 256) {   // 512 float4s, 2/thread
            int r  = q >> 2;
            int kk = (q & 3) * 4;
            float4 v = *reinterpret_cast<const float4*>(Mmat + (size_t)(bm0 + r) * LDM + k0 + kk);
            Ms[kk + 0][r] = v.x; Ms[kk + 1][r] = v.y;
            Ms[kk + 2][r] = v.z; Ms[kk + 3][r] = v.w;
        }
        // stage W tile (128 output-cols x 16 k) -> transposed LDS
        #pragma unroll
        for (int q = t; q < BN * BK / 4; q += 256) {
            int r  = q >> 2;
            int kk = (q & 3) * 4;
            float4 v = *reinterpret_cast<const float4*>(Wbase + (size_t)r * LDW + k0 + kk);
            Ns[kk + 0][r] = v.x; Ns[kk + 1][r] = v.y;
            Ns[kk + 2][r] = v.z; Ns[kk + 3][r] = v.w;
        }
        __syncthreads();

        #pragma unroll
        for (int k = 0; k < BK; ++k) {
            float rm[8], rn[8];
            *reinterpret_cast<float4*>(rm)     = *reinterpret_cast<const float4*>(&Ms[k][ty * 8]);
            *reinterpret_cast<float4*>(rm + 4) = *reinterpret_cast<const float4*>(&Ms[k][ty * 8 + 4]);
            *reinterpret_cast<float4*>(rn)     = *reinterpret_cast<const float4*>(&Ns[k][tx * 8]);
            *reinterpret_cast<float4*>(rn + 4) = *reinterpret_cast<const float4*>(&Ns[k][tx * 8 + 4]);
            #pragma unroll
            for (int i = 0; i < 8; ++i)
                #pragma unroll
                for (int j = 0; j < 8; ++j)
                    acc[i][j] += rm[i] * rn[j];
        }
        __syncthreads();
    }

    #pragma unroll
    for (int i = 0; i < 8; ++i) {
        float* dst = D + (size_t)(bm0 + ty * 8 + i) * LDD + bn0 + tx * 8;
        *reinterpret_cast<float4*>(dst)     = make_float4(acc[i][0], acc[i][1], acc[i][2], acc[i][3]);
        *reinterpret_cast<float4*>(dst + 4) = make_float4(acc[i][4], acc[i][5], acc[i][6], acc[i][7]);
    }
}

// ---------------------------------------------------------------------------
// Combine: out[b,p,h] = tanh(A[b,i,h] + C[b,j,h] + bias[h])
//   A = D[.., :768], C = D[.., 768:]. One block per (p, b); 192 threads,
//   one float4 (4 h-values) per thread. Pure write-BW bound.
// ---------------------------------------------------------------------------
__global__ __launch_bounds__(192) void combine_kernel(
    const float* __restrict__ D,      // [1536][1536]
    const float* __restrict__ bias,   // [768]
    float* __restrict__ out)          // [B][P][768]
{
    const int p = blockIdx.x;
    const int b = blockIdx.y;
    int i, j;
    pair_from_p(p, i, j);

    const int h = threadIdx.x * 4;
    const float4 a  = *reinterpret_cast<const float4*>(D + (size_t)(b * L_SEQ + i) * NCOLS + h);
    const float4 c  = *reinterpret_cast<const float4*>(D + (size_t)(b * L_SEQ + j) * NCOLS + H_DIM + h);
    const float4 bb = *reinterpret_cast<const float4*>(bias + h);

    float4 o;
    o.x = tanhf(a.x + c.x + bb.x);
    o.y = tanhf(a.y + c.y + bb.y);
    o.z = tanhf(a.z + c.z + bb.z);
    o.w = tanhf(a.w + c.w + bb.w);

    *reinterpret_cast<float4*>(out + ((size_t)b * NPAIR + p) * H_DIM + h) = o;
}

// ---------------------------------------------------------------------------
// Fallback (only if ws_size is too small): direct einsum, slow but correct.
// ---------------------------------------------------------------------------
__global__ __launch_bounds__(256) void naive_kernel(
    const float* __restrict__ seq,
    const float* __restrict__ W,
    const float* __restrict__ bias,
    float* __restrict__ out)
{
    const int p = blockIdx.x;
    const int b = blockIdx.y;
    int i, j;
    pair_from_p(p, i, j);
    const float* si = seq + ((size_t)b * L_SEQ + i) * H_DIM;
    const float* sj = seq + ((size_t)b * L_SEQ + j) * H_DIM;
    for (int h = threadIdx.x; h < H_DIM; h += 256) {
        const float* wr = W + (size_t)h * NCOLS;
        float s = bias[h];
        for (int k = 0; k < H_DIM; ++k)
            s += si[k] * wr[k] + sj[k] * wr[H_DIM + k];
        out[((size_t)b * NPAIR + p) * H_DIM + h] = tanhf(s);
    }
}

extern "C" void kernel_launch(void* const* d_in, const int* in_sizes, int n_in,
                              void* d_out, int out_size, void* d_ws, size_t ws_size,
                              hipStream_t stream) {
    const float* seq  = (const float*)d_in[0];   // [8][192][768]
    const float* W    = (const float*)d_in[1];   // [768][1536]
    const float* bias = (const float*)d_in[2];   // [768]
    float* out = (float*)d_out;                  // [8][18528][768]

    const size_t need = (size_t)MROWS * NCOLS * sizeof(float);   // 9.4 MB
    if (ws_size >= need) {
        float* D = (float*)d_ws;
        dim3 g1(NCOLS / BN, MROWS / BM);   // 12 x 12
        hipLaunchKernelGGL(gemm_f32_kernel, g1, dim3(256), 0, stream, seq, W, D);
        dim3 g2(NPAIR, B_SZ);              // 18528 x 8
        hipLaunchKernelGGL(combine_kernel, g2, dim3(192), 0, stream, D, bias, out);
    } else {
        dim3 g(NPAIR, B_SZ);
        hipLaunchKernelGGL(naive_kernel, g, dim3(256), 0, stream, seq, W, bias, out);
    }
}

// Round 3
// 137.636 us; speedup vs baseline: 2.0485x; 2.0485x over previous
//
#include <hip/hip_runtime.h>
#include <math.h>

#define L_SEQ 192
#define H_DIM 768
#define B_SZ  8
#define NPAIR (L_SEQ * (L_SEQ + 1) / 2)   // 18528
#define MROWS (B_SZ * L_SEQ)              // 1536
#define NCOLS (2 * H_DIM)                 // 1536 (D columns: [A | C])

typedef short  bf16x8  __attribute__((ext_vector_type(8)));
typedef float  f32x4   __attribute__((ext_vector_type(4)));
typedef unsigned short u16x4 __attribute__((ext_vector_type(4)));

// p -> (i, j) for triu_indices(L) in row-major order.
__device__ __forceinline__ void pair_from_p(int p, int& io, int& jo) {
    float tl = 2.0f * L_SEQ + 1.0f;
    int i = (int)((tl - sqrtf(tl * tl - 8.0f * (float)p)) * 0.5f);
    if (i < 0) i = 0;
    if (i > L_SEQ - 1) i = L_SEQ - 1;
    while (i > 0 && i * (2 * L_SEQ - i + 1) / 2 > p) --i;
    while (i < L_SEQ - 1 && (i + 1) * (2 * L_SEQ - i) / 2 <= p) ++i;
    io = i;
    jo = i + (p - i * (2 * L_SEQ - i + 1) / 2);
}

struct HL { unsigned short h, l; };

// Split f32 into hi bf16 (RTN) + lo bf16 (RTN of residual). x ~= hi + lo with
// ~2^-17 relative error; the dropped lo*lo MFMA term contributes ~1e-5 absmax.
__device__ __forceinline__ HL split_bf16(float x) {
    HL r;
    unsigned u  = __float_as_uint(x);
    unsigned rh = u + 0x7FFFu + ((u >> 16) & 1u);
    r.h = (unsigned short)(rh >> 16);
    float hf = __uint_as_float((unsigned)r.h << 16);
    float res = x - hf;
    unsigned u2 = __float_as_uint(res);
    unsigned rl = u2 + 0x7FFFu + ((u2 >> 16) & 1u);
    r.l = (unsigned short)(rl >> 16);
    return r;
}

// tanh(x) = 1 - 2/(e^{2x}+1); exp2 + rcp are single HW instructions.
// Saturates correctly: x>>0 -> exp2->inf -> rcp->0 -> 1; x<<0 -> exp2->0 -> -1.
__device__ __forceinline__ float fast_tanh(float x) {
    float e = __builtin_amdgcn_exp2f(x * 2.885390081777927f);  // 2*log2(e)
    return 1.0f - 2.0f * __builtin_amdgcn_rcpf(e + 1.0f);
}

// ---------------------------------------------------------------------------
// Split-bf16 MFMA GEMM: D[m][n] = sum_k seq[m][k] * W[n&767][(n>=768)*768+k]
// BM=BN=128, BK=32, 256 threads = 4 waves (2x2), each wave 64x64 via 4x4
// frags of 16x16x32. 3 MFMAs per frag pair (hi*hi + hi*lo + lo*hi).
// LDS pitch 40 shorts (32 + 8 pad): row stride 80 B.
// ---------------------------------------------------------------------------
#define LDSP 40

__global__ __launch_bounds__(256) void gemm_mfma_kernel(
    const float* __restrict__ seq,   // [1536][768]
    const float* __restrict__ W,     // [768][1536]
    float* __restrict__ D)           // [1536][1536]
{
    __shared__ unsigned short Ah[128 * LDSP], Al[128 * LDSP];
    __shared__ unsigned short Bh[128 * LDSP], Bl[128 * LDSP];

    const int t    = threadIdx.x;
    const int bn0  = blockIdx.x * 128;
    const int bm0  = blockIdx.y * 128;
    const int side = (bn0 >= H_DIM) ? 1 : 0;     // uniform per block (768%128==0)
    const int wrow0 = bn0 - side * H_DIM;        // W row base for this col-tile
    const int kofs  = side * H_DIM;              // k offset inside W row

    const int lane = t & 63;
    const int wave = t >> 6;
    const int wr   = wave >> 1, wc = wave & 1;   // 2x2 wave grid
    const int l15  = lane & 15;
    const int kc   = (lane >> 4) * 8;            // frag k-base within BK=32

    // staging: thread t covers row sr, k-half sk (16 floats)
    const int sr = t >> 1;
    const int sk = (t & 1) * 16;

    f32x4 acc[4][4];
    #pragma unroll
    for (int a = 0; a < 4; ++a)
        #pragma unroll
        for (int b = 0; b < 4; ++b) acc[a][b] = (f32x4){0.f, 0.f, 0.f, 0.f};

    for (int k0 = 0; k0 < H_DIM; k0 += 32) {
        // ---- stage A tile: seq rows, f32 -> (hi,lo) bf16
        {
            const float* src = seq + (size_t)(bm0 + sr) * H_DIM + k0 + sk;
            unsigned short* dh = Ah + sr * LDSP + sk;
            unsigned short* dl = Al + sr * LDSP + sk;
            #pragma unroll
            for (int c = 0; c < 4; ++c) {
                float4 v = *reinterpret_cast<const float4*>(src + c * 4);
                HL sx = split_bf16(v.x), sy = split_bf16(v.y);
                HL sz = split_bf16(v.z), sw = split_bf16(v.w);
                u16x4 h = {sx.h, sy.h, sz.h, sw.h};
                u16x4 l = {sx.l, sy.l, sz.l, sw.l};
                *reinterpret_cast<u16x4*>(dh + c * 4) = h;
                *reinterpret_cast<u16x4*>(dl + c * 4) = l;
            }
        }
        // ---- stage B tile: W rows (output cols), same pattern
        {
            const float* src = W + (size_t)(wrow0 + sr) * NCOLS + kofs + k0 + sk;
            unsigned short* dh = Bh + sr * LDSP + sk;
            unsigned short* dl = Bl + sr * LDSP + sk;
            #pragma unroll
            for (int c = 0; c < 4; ++c) {
                float4 v = *reinterpret_cast<const float4*>(src + c * 4);
                HL sx = split_bf16(v.x), sy = split_bf16(v.y);
                HL sz = split_bf16(v.z), sw = split_bf16(v.w);
                u16x4 h = {sx.h, sy.h, sz.h, sw.h};
                u16x4 l = {sx.l, sy.l, sz.l, sw.l};
                *reinterpret_cast<u16x4*>(dh + c * 4) = h;
                *reinterpret_cast<u16x4*>(dl + c * 4) = l;
            }
        }
        __syncthreads();

        // ---- fragment loads (A: row = lane&15, k = (lane>>4)*8 + r; B: col likewise)
        bf16x8 ah[4], al[4], bh[4], bl[4];
        #pragma unroll
        for (int mi = 0; mi < 4; ++mi) {
            int row = wr * 64 + mi * 16 + l15;
            ah[mi] = *reinterpret_cast<const bf16x8*>(Ah + row * LDSP + kc);
            al[mi] = *reinterpret_cast<const bf16x8*>(Al + row * LDSP + kc);
        }
        #pragma unroll
        for (int ni = 0; ni < 4; ++ni) {
            int row = wc * 64 + ni * 16 + l15;
            bh[ni] = *reinterpret_cast<const bf16x8*>(Bh + row * LDSP + kc);
            bl[ni] = *reinterpret_cast<const bf16x8*>(Bl + row * LDSP + kc);
        }

        #pragma unroll
        for (int mi = 0; mi < 4; ++mi)
            #pragma unroll
            for (int ni = 0; ni < 4; ++ni) {
                acc[mi][ni] = __builtin_amdgcn_mfma_f32_16x16x32_bf16(ah[mi], bh[ni], acc[mi][ni], 0, 0, 0);
                acc[mi][ni] = __builtin_amdgcn_mfma_f32_16x16x32_bf16(ah[mi], bl[ni], acc[mi][ni], 0, 0, 0);
                acc[mi][ni] = __builtin_amdgcn_mfma_f32_16x16x32_bf16(al[mi], bh[ni], acc[mi][ni], 0, 0, 0);
            }
        __syncthreads();
    }

    // ---- epilogue: C/D layout col = lane&15, row = (lane>>4)*4 + r  [m89/m91]
    #pragma unroll
    for (int mi = 0; mi < 4; ++mi)
        #pragma unroll
        for (int ni = 0; ni < 4; ++ni) {
            int row0 = bm0 + wr * 64 + mi * 16 + (lane >> 4) * 4;
            int col  = bn0 + wc * 64 + ni * 16 + l15;
            #pragma unroll
            for (int r = 0; r < 4; ++r)
                D[(size_t)(row0 + r) * NCOLS + col] = acc[mi][ni][r];
        }
}

// ---------------------------------------------------------------------------
// Combine: out[b,p,h] = tanh(A[b,i,h] + C[b,j,h] + bias[h])
// One block per p, 192 threads (one float4 of h each), loop over all 8 b:
// amortizes pair math, gives 8-deep ILP. nontemporal stores keep the 455 MB
// output from evicting D out of L2/L3.
// ---------------------------------------------------------------------------
__global__ __launch_bounds__(192) void combine_kernel(
    const float* __restrict__ D,      // [1536][1536]
    const float* __restrict__ bias,   // [768]
    float* __restrict__ out)          // [B][P][768]
{
    const int p = blockIdx.x;
    int i, j;
    pair_from_p(p, i, j);

    const int h = threadIdx.x * 4;
    const f32x4 bb = *reinterpret_cast<const f32x4*>(bias + h);

    #pragma unroll
    for (int b = 0; b < B_SZ; ++b) {
        const f32x4 a = *reinterpret_cast<const f32x4*>(D + (size_t)(b * L_SEQ + i) * NCOLS + h);
        const f32x4 c = *reinterpret_cast<const f32x4*>(D + (size_t)(b * L_SEQ + j) * NCOLS + H_DIM + h);
        f32x4 o;
        o.x = fast_tanh(a.x + c.x + bb.x);
        o.y = fast_tanh(a.y + c.y + bb.y);
        o.z = fast_tanh(a.z + c.z + bb.z);
        o.w = fast_tanh(a.w + c.w + bb.w);
        __builtin_nontemporal_store(o, reinterpret_cast<f32x4*>(out + ((size_t)b * NPAIR + p) * H_DIM + h));
    }
}

// ---------------------------------------------------------------------------
// Fallback (only if ws_size too small): direct einsum, slow but correct.
// ---------------------------------------------------------------------------
__global__ __launch_bounds__(256) void naive_kernel(
    const float* __restrict__ seq,
    const float* __restrict__ W,
    const float* __restrict__ bias,
    float* __restrict__ out)
{
    const int p = blockIdx.x;
    const int b = blockIdx.y;
    int i, j;
    pair_from_p(p, i, j);
    const float* si = seq + ((size_t)b * L_SEQ + i) * H_DIM;
    const float* sj = seq + ((size_t)b * L_SEQ + j) * H_DIM;
    for (int h = threadIdx.x; h < H_DIM; h += 256) {
        const float* wr = W + (size_t)h * NCOLS;
        float s = bias[h];
        for (int k = 0; k < H_DIM; ++k)
            s += si[k] * wr[k] + sj[k] * wr[H_DIM + k];
        out[((size_t)b * NPAIR + p) * H_DIM + h] = tanhf(s);
    }
}

extern "C" void kernel_launch(void* const* d_in, const int* in_sizes, int n_in,
                              void* d_out, int out_size, void* d_ws, size_t ws_size,
                              hipStream_t stream) {
    const float* seq  = (const float*)d_in[0];   // [8][192][768]
    const float* W    = (const float*)d_in[1];   // [768][1536]
    const float* bias = (const float*)d_in[2];   // [768]
    float* out = (float*)d_out;                  // [8][18528][768]

    const size_t need = (size_t)MROWS * NCOLS * sizeof(float);   // 9.4 MB
    if (ws_size >= need) {
        float* D = (float*)d_ws;
        dim3 g1(NCOLS / 128, MROWS / 128);   // 12 x 12
        hipLaunchKernelGGL(gemm_mfma_kernel, g1, dim3(256), 0, stream, seq, W, D);
        hipLaunchKernelGGL(combine_kernel, dim3(NPAIR), dim3(192), 0, stream, D, bias, out);
    } else {
        dim3 g(NPAIR, B_SZ);
        hipLaunchKernelGGL(naive_kernel, g, dim3(256), 0, stream, seq, W, bias, out);
    }
}